// Round 2
// baseline (517.988 us; speedup 1.0000x reference)
//
#include <hip/hip_runtime.h>

// CostVolume1D: out[n,i,h,w] = (1/C) * sum_c f1[n,c,h,w] * f2pad[n,c,h,w+i-4]
// N=4, C=128, H=192, W=640, D=4 -> 9 shifts. Memory-bound.
//
// R2 design: wave-autonomous, ZERO barriers / ZERO LDS.
// W=640 = 5 segments x (64 lanes x float2). Each wave owns one (n,h,seg)
// tile; each lane owns floats [w0, w0+1] and loads its f2 window
// [w0-4, w0+5] as 5 aligned float2 loads (L1 absorbs the 5x overlap; HBM
// traffic is unchanged - same cache lines). Row-edge zero padding via an
// unsigned bound check (divergent only on edge lanes). Register-level
// double-buffered prefetch, distance = 2 channels; no s_barrier anywhere,
// so vmcnt never has to drain and waves pipeline freely.

constexpr int DD = 4;
constexpr int NS = 2 * DD + 1;          // 9
constexpr int N_ = 4, C_ = 128, H_ = 192, W_ = 640;
constexpr int HW = H_ * W_;
constexpr int SEGS  = W_ / 128;         // 5 wave-segments per row
constexpr int TILES = N_ * H_ * SEGS;   // 3840 wave-tiles
constexpr int WPB   = 4;                // waves per block (256 threads)
constexpr int NBLK  = TILES / WPB;      // 960 blocks

__global__ __launch_bounds__(256)
void cost_volume_kernel(const float* __restrict__ f1,
                        const float* __restrict__ f2,
                        float* __restrict__ out)
{
    const int lane = threadIdx.x & 63;
    const int wid  = blockIdx.x * WPB + (threadIdx.x >> 6);
    const int seg  = wid % SEGS;
    const int row  = wid / SEGS;            // n*H + h
    const int n    = row / H_;
    const int h    = row - n * H_;
    const int w0   = seg * 128 + lane * 2;  // this lane's w in [0, 640)

    const size_t base = (size_t)n * C_ * HW + (size_t)h * W_;
    const float* f1p = f1 + base + w0;      // + c*HW per channel
    const float* f2p = f2 + base;           // + c*HW + (w0-4+2k)

    // register pipeline, depth 2
    float2 A[2];
    float2 B[2][5];

    auto load_stage = [&](int st, int c) {
        const float* f1c = f1p + (size_t)c * HW;
        const float* f2c = f2p + (size_t)c * HW;
        A[st] = *(const float2*)f1c;
#pragma unroll
        for (int k = 0; k < 5; ++k) {
            const int off = w0 - 4 + 2 * k;       // even; pair fully in/out
            float2 v = make_float2(0.f, 0.f);
            if ((unsigned)off <= (unsigned)(W_ - 2))
                v = *(const float2*)(f2c + off);
            B[st][k] = v;
        }
    };

    float acc0[NS], acc1[NS];
#pragma unroll
    for (int i = 0; i < NS; ++i) { acc0[i] = 0.f; acc1[i] = 0.f; }

    load_stage(0, 0);
    load_stage(1, 1);

#pragma unroll 2
    for (int c = 0; c < C_; ++c) {
        const int st = c & 1;
        const float2 a = A[st];
        float v[10];
#pragma unroll
        for (int k = 0; k < 5; ++k) { v[2*k] = B[st][k].x; v[2*k+1] = B[st][k].y; }

#pragma unroll
        for (int i = 0; i < NS; ++i) {
            acc0[i] = fmaf(a.x, v[i],     acc0[i]);
            acc1[i] = fmaf(a.y, v[i + 1], acc1[i]);
        }

        if (c + 2 < C_) load_stage(st, c + 2);   // uniform branch
    }

    constexpr float scale = 1.0f / (float)C_;
    float* orow = out + (size_t)n * NS * HW + (size_t)h * W_ + w0;
#pragma unroll
    for (int i = 0; i < NS; ++i) {
        float2 o;
        o.x = acc0[i] * scale;
        o.y = acc1[i] * scale;
        *(float2*)(orow + (size_t)i * HW) = o;
    }
}

extern "C" void kernel_launch(void* const* d_in, const int* in_sizes, int n_in,
                              void* d_out, int out_size, void* d_ws, size_t ws_size,
                              hipStream_t stream) {
    const float* f1 = (const float*)d_in[0];
    const float* f2 = (const float*)d_in[1];
    float* out = (float*)d_out;
    cost_volume_kernel<<<dim3(NBLK), dim3(256), 0, stream>>>(f1, f2, out);
}